// Round 22
// baseline (44.998 us; speedup 1.0000x reference)
//
#include <hip/hip_runtime.h>
#include <cstdint>
#include <cstddef>

// ContrastiveLoss: B=8192, D=256 fp32 inputs.
// loss = mean_b [ log( exp(2*pos_b) + sum_c exp(2*z_i[b].z_k[c]) ) - 2*pos_b ]
// R21: R20 + flat-grid residency swizzle. bid 1-D; bC = bid & 15,
// bR = bid >> 4. Co-resident blocks {c, c+256, c+512, c+768} share bC
// (256 % 16 == 0) -> all 16 waves on a CU read the SAME B fragments ->
// L1 hits after first touch. Kernel body identical to R19/R20 (verified):
// 32x32 wave tile, A in regs, B ring depth 4, no LDS, no barriers, exp2.

constexpr int   D_DIM = 256;
constexpr float INV_T = 2.0f;        // 1/T, T=0.5
constexpr float LOG2E = 1.44269504f;

constexpr int BM = 128;         // block rows
constexpr int NT = 16;          // col-tiles per block (each 32 cols)

typedef __attribute__((ext_vector_type(8)))  int   i32x8;
typedef __attribute__((ext_vector_type(4)))  int   i32x4;
typedef __attribute__((ext_vector_type(16))) float f32x16;

// ---------------------------------------------------------------------------
// Kernel 1: per-16-row group: norms, pos_logit, rowsum init, PACKED e4m3 out.
// (unchanged — verified correct)
// Split-half pack: frag f = (row>>5)*4 + (c>>2);
//   lane = (row&31) + 32*((c>>1)&1); half = c&1;
//   byte = f*2048 + half*1024 + lane*16.
// z_i additionally scaled by LOG2E (so GEMM's scale-A=2.0 yields exp2 arg).
// ---------------------------------------------------------------------------
__global__ __launch_bounds__(256) void prep_kernel(
    const float* __restrict__ ei, const float* __restrict__ ej,
    const float* __restrict__ ek,
    unsigned char* __restrict__ zip, unsigned char* __restrict__ zkp,
    float* __restrict__ pos_logit, float* __restrict__ rowsum)
{
    const int t  = (int)threadIdx.x;
    const int rl = t >> 4;              // row within group (0..15)
    const int c  = t & 15;              // 16-elem chunk (0..15)
    const int g  = (int)blockIdx.x;     // 16-row group
    const int row = g * 16 + rl;

    const float4* pi = (const float4*)(ei + (size_t)row * D_DIM + c * 16);
    const float4* pj = (const float4*)(ej + (size_t)row * D_DIM + c * 16);
    const float4* pk = (const float4*)(ek + (size_t)row * D_DIM + c * 16);
    float4 vi[4], vj[4], vk[4];
    #pragma unroll
    for (int q = 0; q < 4; ++q) { vi[q] = pi[q]; vj[q] = pj[q]; vk[q] = pk[q]; }

    float ssi = 0.f, ssj = 0.f, ssk = 0.f, dij = 0.f;
    #pragma unroll
    for (int q = 0; q < 4; ++q) {
        ssi += vi[q].x*vi[q].x + vi[q].y*vi[q].y + vi[q].z*vi[q].z + vi[q].w*vi[q].w;
        ssj += vj[q].x*vj[q].x + vj[q].y*vj[q].y + vj[q].z*vj[q].z + vj[q].w*vj[q].w;
        ssk += vk[q].x*vk[q].x + vk[q].y*vk[q].y + vk[q].z*vk[q].z + vk[q].w*vk[q].w;
        dij += vi[q].x*vj[q].x + vi[q].y*vj[q].y + vi[q].z*vj[q].z + vi[q].w*vj[q].w;
    }
    #pragma unroll
    for (int off = 1; off <= 8; off <<= 1) {    // reduce over the 16 c-lanes
        ssi += __shfl_xor(ssi, off);
        ssj += __shfl_xor(ssj, off);
        ssk += __shfl_xor(ssk, off);
        dij += __shfl_xor(dij, off);
    }
    const float rn = 1.0f / fmaxf(sqrtf(ssi), 1e-12f);
    const float ri = rn * LOG2E;                          // fold log2(e)
    const float rj = 1.0f / fmaxf(sqrtf(ssj), 1e-12f);
    const float rk = 1.0f / fmaxf(sqrtf(ssk), 1e-12f);

    uint4 uiv, ukv;
    {
        unsigned int wi[4], wk[4];
        #pragma unroll
        for (int q = 0; q < 4; ++q) {
            const float* fi = &vi[q].x;
            const float* fk = &vk[q].x;
            int a = 0, b = 0;
            a = __builtin_amdgcn_cvt_pk_fp8_f32(fi[0] * ri, fi[1] * ri, a, false);
            a = __builtin_amdgcn_cvt_pk_fp8_f32(fi[2] * ri, fi[3] * ri, a, true);
            b = __builtin_amdgcn_cvt_pk_fp8_f32(fk[0] * rk, fk[1] * rk, b, false);
            b = __builtin_amdgcn_cvt_pk_fp8_f32(fk[2] * rk, fk[3] * rk, b, true);
            wi[q] = (unsigned int)a;
            wk[q] = (unsigned int)b;
        }
        uiv = make_uint4(wi[0], wi[1], wi[2], wi[3]);
        ukv = make_uint4(wk[0], wk[1], wk[2], wk[3]);
    }
    const int f    = (row >> 5) * 4 + (c >> 2);
    const int lane = (row & 31) + 32 * ((c >> 1) & 1);
    const size_t off = (size_t)f * 2048 + (c & 1) * 1024 + lane * 16;
    *(uint4*)(zip + off) = uiv;
    *(uint4*)(zkp + off) = ukv;

    if (c == 0) {
        pos_logit[row] = dij * rn * rj * INV_T;   // plain 2*(zi.zj), no log2e
        rowsum[row]    = 0.0f;
    }
}

// ---------------------------------------------------------------------------
// Kernel 2: rows [bR*128,+128) x cols [bC*512,+512) of exp2-sum of
// 2*log2e*(z_i . z_k). Flat grid; bC = bid & 15 (so co-resident blocks
// share the B panel -> L1 hits), bR = bid >> 4.
// 4 waves = row slices; wave tile 32x32; 64 steps fully unrolled.
// A: 4 frags in registers (loaded once). B: ring depth 4. No LDS/barriers.
// ---------------------------------------------------------------------------
__global__ __launch_bounds__(256) void sim_mfma_kernel(
    const unsigned char* __restrict__ zip, const unsigned char* __restrict__ zkp,
    float* __restrict__ rowsum)
{
    const int t  = (int)threadIdx.x;
    const int w  = t >> 6;        // wave 0..3 = row slice
    const int l  = t & 63;
    const int bid = (int)blockIdx.x;
    const int bC = bid & 15;           // col block (same across co-resident)
    const int bR = bid >> 4;           // row block
    const int rowBase = bR * BM;

    // ---- A frags -> registers (once): global frag (bR*4+w)*4 + kt.
    const unsigned char* Abase =
        zip + ((size_t)(bR * 4 + w) * 4) * 2048 + (size_t)l * 16;
    #define LDFRAG(dst, base, fb_) {                                          \
        i32x4 lo_ = *(const i32x4*)((base) + (fb_));                          \
        i32x4 hi_ = *(const i32x4*)((base) + (fb_) + 1024);                   \
        dst = (i32x8){lo_[0], lo_[1], lo_[2], lo_[3],                         \
                      hi_[0], hi_[1], hi_[2], hi_[3]};                        \
    }
    i32x8 a0, a1, a2, a3;
    LDFRAG(a0, Abase, 0);
    LDFRAG(a1, Abase, 2048);
    LDFRAG(a2, Abase, 4096);
    LDFRAG(a3, Abase, 6144);

    // ---- B frag (global, split-half): frag s (= nt*4+kt) at Bbase+s*2048.
    const unsigned char* Bbase =
        zkp + ((size_t)bC * 16 * 4) * 2048 + (size_t)l * 16;

    // ---- B ring, depth 4 (static names; slot = s & 3) ----
    i32x8 b0, b1, b2, b3;
    LDFRAG(b0, Bbase, 0);
    LDFRAG(b1, Bbase, 2048);
    LDFRAG(b2, Bbase, 4096);
    LDFRAG(b3, Bbase, 6144);

    float partAcc[16] = {};

    #pragma unroll
    for (int nt = 0; nt < NT; ++nt) {
        f32x16 acc = {};

        #pragma unroll
        for (int k4 = 0; k4 < 4; ++k4) {
            const int s  = nt * 4 + k4;           // compile-time
            const int s4 = (s + 4 > NT * 4 - 1) ? (NT * 4 - 1) : (s + 4);

            __builtin_amdgcn_s_setprio(1);
            acc = __builtin_amdgcn_mfma_scale_f32_32x32x64_f8f6f4(
                (k4 == 0) ? a0 : (k4 == 1) ? a1 : (k4 == 2) ? a2 : a3,
                (s % 4 == 0) ? b0 : (s % 4 == 1) ? b1
                             : (s % 4 == 2) ? b2 : b3,
                acc,
                0, 0,                 // cbsz=fp8(A), blgp=fp8(B)
                0, 0x00000080,        // scale A = 2.0 (1/T)
                0, 0x0000007F);       // scale B = 1.0
            __builtin_amdgcn_s_setprio(0);

            // refill this slot for step s+4 (distance 4)
            if (s % 4 == 0)      { LDFRAG(b0, Bbase, (size_t)s4 * 2048); }
            else if (s % 4 == 1) { LDFRAG(b1, Bbase, (size_t)s4 * 2048); }
            else if (s % 4 == 2) { LDFRAG(b2, Bbase, (size_t)s4 * 2048); }
            else                 { LDFRAG(b3, Bbase, (size_t)s4 * 2048); }
        }

        // per-tile epilogue: bare exp2 + in-lane partial sums
        #pragma unroll
        for (int r = 0; r < 16; ++r)
            partAcc[r] += exp2f(acc[r]);
    }
    #undef LDFRAG

    // wave epilogue: reduce across the 32 column-lanes (xor<32 stays in half)
    #pragma unroll
    for (int off = 1; off <= 16; off <<= 1)
        #pragma unroll
        for (int r = 0; r < 16; ++r)
            partAcc[r] += __shfl_xor(partAcc[r], off);

    if ((l & 31) == 0) {
        const int hi = l >> 5;           // C/D: row = (r&3) + 8*(r>>2) + 4*hi
        #pragma unroll
        for (int r = 0; r < 16; ++r) {
            const int rr = (r & 3) + 8 * (r >> 2) + 4 * hi;
            atomicAdd(&rowsum[rowBase + w * 32 + rr], partAcc[r]);
        }
    }
}

// ---------------------------------------------------------------------------
// Kernel 3: loss = mean_b [ log(exp(pos_b) + rowsum_b) - pos_b ]
// ---------------------------------------------------------------------------
__global__ __launch_bounds__(1024) void finalize_kernel(
    const float* __restrict__ pos_logit, const float* __restrict__ rowsum,
    float* __restrict__ out, int B)
{
    __shared__ float red[1024];
    float acc = 0.f;
    for (int b = (int)threadIdx.x; b < B; b += 1024) {
        const float pl = pos_logit[b];
        acc += logf(expf(pl) + rowsum[b]) - pl;
    }
    red[threadIdx.x] = acc;
    __syncthreads();
    #pragma unroll
    for (int s = 512; s; s >>= 1) {
        if ((int)threadIdx.x < s) red[threadIdx.x] += red[threadIdx.x + s];
        __syncthreads();
    }
    if (threadIdx.x == 0) out[0] = red[0] / (float)B;
}

// ---------------------------------------------------------------------------
extern "C" void kernel_launch(void* const* d_in, const int* in_sizes, int n_in,
                              void* d_out, int out_size, void* d_ws, size_t ws_size,
                              hipStream_t stream)
{
    const float* ei = (const float*)d_in[0];
    const float* ej = (const float*)d_in[1];
    const float* ek = (const float*)d_in[2];
    const int B = in_sizes[0] / D_DIM;   // 8192

    unsigned char* zip = (unsigned char*)d_ws;              // 2 MB packed fp8
    unsigned char* zkp = zip + (size_t)B * D_DIM;           // 2 MB packed fp8
    float* rowsum      = (float*)(zkp + (size_t)B * D_DIM);
    float* pos_logit   = rowsum + B;

    prep_kernel<<<dim3(B / 16), dim3(256), 0, stream>>>(
        ei, ej, ek, zip, zkp, pos_logit, rowsum);

    // flat grid: bC = bid & 15, bR = bid >> 4 (co-resident blocks share bC)
    sim_mfma_kernel<<<dim3((B / BM) * (B / (NT * 32))), dim3(256), 0, stream>>>(
        zip, zkp, rowsum);

    finalize_kernel<<<dim3(1), dim3(1024), 0, stream>>>(
        pos_logit, rowsum, (float*)d_out, B);
}

// Round 23
// 41.816 us; speedup vs baseline: 1.0761x; 1.0761x over previous
//
#include <hip/hip_runtime.h>
#include <cstdint>
#include <cstddef>

// ContrastiveLoss: B=8192, D=256 fp32 inputs.
// loss = mean_b [ log( exp(2*pos_b) + sum_c exp(2*z_i[b].z_k[c]) ) - 2*pos_b ]
// R22: best-known config = R20 grid (x = row block fast -> XCD-L2 holds one
// B panel at a time) + R14's CONTIGUOUS 32 B/lane fragment layout (split-half
// was an LDS-era artifact; with no LDS, contiguous loads = single i32x8
// deref, no element-insert movs). Body otherwise identical to R19/R20:
// 32x32 wave tile, A in regs (loaded once), B ring depth 4, no LDS, no
// barriers, exp2 epilogue, lane-reduce + atomics once per wave.

constexpr int   D_DIM = 256;
constexpr float INV_T = 2.0f;        // 1/T, T=0.5
constexpr float LOG2E = 1.44269504f;

constexpr int BM = 128;         // block rows
constexpr int NT = 16;          // col-tiles per block (each 32 cols)

typedef __attribute__((ext_vector_type(8)))  int   i32x8;
typedef __attribute__((ext_vector_type(16))) float f32x16;

// ---------------------------------------------------------------------------
// Kernel 1: per-16-row group: norms, pos_logit, rowsum init, PACKED e4m3 out.
// Thread t: row_local = t>>4, chunk c = t&15 (16 elems, k in [c*16,+16)).
// CONTIGUOUS pack (R14-verified): frag f = (row>>5)*4 + (c>>2);
//   lane = (row&31) + 32*((c>>1)&1);  byte = f*2048 + lane*32 + (c&1)*16.
// z_i additionally scaled by LOG2E (so GEMM's scale-A=2.0 yields exp2 arg).
// ---------------------------------------------------------------------------
__global__ __launch_bounds__(256) void prep_kernel(
    const float* __restrict__ ei, const float* __restrict__ ej,
    const float* __restrict__ ek,
    unsigned char* __restrict__ zip, unsigned char* __restrict__ zkp,
    float* __restrict__ pos_logit, float* __restrict__ rowsum)
{
    const int t  = (int)threadIdx.x;
    const int rl = t >> 4;              // row within group (0..15)
    const int c  = t & 15;              // 16-elem chunk (0..15)
    const int g  = (int)blockIdx.x;     // 16-row group
    const int row = g * 16 + rl;

    const float4* pi = (const float4*)(ei + (size_t)row * D_DIM + c * 16);
    const float4* pj = (const float4*)(ej + (size_t)row * D_DIM + c * 16);
    const float4* pk = (const float4*)(ek + (size_t)row * D_DIM + c * 16);
    float4 vi[4], vj[4], vk[4];
    #pragma unroll
    for (int q = 0; q < 4; ++q) { vi[q] = pi[q]; vj[q] = pj[q]; vk[q] = pk[q]; }

    float ssi = 0.f, ssj = 0.f, ssk = 0.f, dij = 0.f;
    #pragma unroll
    for (int q = 0; q < 4; ++q) {
        ssi += vi[q].x*vi[q].x + vi[q].y*vi[q].y + vi[q].z*vi[q].z + vi[q].w*vi[q].w;
        ssj += vj[q].x*vj[q].x + vj[q].y*vj[q].y + vj[q].z*vj[q].z + vj[q].w*vj[q].w;
        ssk += vk[q].x*vk[q].x + vk[q].y*vk[q].y + vk[q].z*vk[q].z + vk[q].w*vk[q].w;
        dij += vi[q].x*vj[q].x + vi[q].y*vj[q].y + vi[q].z*vj[q].z + vi[q].w*vj[q].w;
    }
    #pragma unroll
    for (int off = 1; off <= 8; off <<= 1) {    // reduce over the 16 c-lanes
        ssi += __shfl_xor(ssi, off);
        ssj += __shfl_xor(ssj, off);
        ssk += __shfl_xor(ssk, off);
        dij += __shfl_xor(dij, off);
    }
    const float rn = 1.0f / fmaxf(sqrtf(ssi), 1e-12f);
    const float ri = rn * LOG2E;                          // fold log2(e)
    const float rj = 1.0f / fmaxf(sqrtf(ssj), 1e-12f);
    const float rk = 1.0f / fmaxf(sqrtf(ssk), 1e-12f);

    uint4 uiv, ukv;
    {
        unsigned int wi[4], wk[4];
        #pragma unroll
        for (int q = 0; q < 4; ++q) {
            const float* fi = &vi[q].x;
            const float* fk = &vk[q].x;
            int a = 0, b = 0;
            a = __builtin_amdgcn_cvt_pk_fp8_f32(fi[0] * ri, fi[1] * ri, a, false);
            a = __builtin_amdgcn_cvt_pk_fp8_f32(fi[2] * ri, fi[3] * ri, a, true);
            b = __builtin_amdgcn_cvt_pk_fp8_f32(fk[0] * rk, fk[1] * rk, b, false);
            b = __builtin_amdgcn_cvt_pk_fp8_f32(fk[2] * rk, fk[3] * rk, b, true);
            wi[q] = (unsigned int)a;
            wk[q] = (unsigned int)b;
        }
        uiv = make_uint4(wi[0], wi[1], wi[2], wi[3]);
        ukv = make_uint4(wk[0], wk[1], wk[2], wk[3]);
    }
    const int f    = (row >> 5) * 4 + (c >> 2);
    const int lane = (row & 31) + 32 * ((c >> 1) & 1);
    const size_t off = (size_t)f * 2048 + lane * 32 + (c & 1) * 16;
    *(uint4*)(zip + off) = uiv;
    *(uint4*)(zkp + off) = ukv;

    if (c == 0) {
        pos_logit[row] = dij * rn * rj * INV_T;   // plain 2*(zi.zj), no log2e
        rowsum[row]    = 0.0f;
    }
}

// ---------------------------------------------------------------------------
// Kernel 2: rows [bR*128,+128) x cols [bC*512,+512) of exp2-sum of
// 2*log2e*(z_i . z_k); bR = blockIdx.x (FAST), bC = blockIdx.y.
// 4 waves = row slices; wave tile 32x32; 64 steps fully unrolled.
// A: 4 frags in registers (loaded once, contiguous 32 B/lane -> one i32x8
// deref each). B: ring depth 4, same layout. No LDS, no barriers.
// ---------------------------------------------------------------------------
__global__ __launch_bounds__(256) void sim_mfma_kernel(
    const unsigned char* __restrict__ zip, const unsigned char* __restrict__ zkp,
    float* __restrict__ rowsum)
{
    const int t  = (int)threadIdx.x;
    const int w  = t >> 6;        // wave 0..3 = row slice
    const int l  = t & 63;
    const int bR = (int)blockIdx.x;    // row block (fast)
    const int bC = (int)blockIdx.y;    // col block
    const int rowBase = bR * BM;

    // ---- A frags -> registers (once): global frag (bR*4+w)*4 + kt.
    const unsigned char* Abase =
        zip + ((size_t)(bR * 4 + w) * 4) * 2048 + (size_t)l * 32;
    i32x8 a0 = *(const i32x8*)(Abase);
    i32x8 a1 = *(const i32x8*)(Abase + 2048);
    i32x8 a2 = *(const i32x8*)(Abase + 4096);
    i32x8 a3 = *(const i32x8*)(Abase + 6144);

    // ---- B frag: frag s (= nt*4+kt) at Bbase + s*2048 (contiguous 32B/lane)
    const unsigned char* Bbase =
        zkp + ((size_t)bC * 16 * 4) * 2048 + (size_t)l * 32;

    // ---- B ring, depth 4 (static names; slot = s & 3) ----
    i32x8 b0 = *(const i32x8*)(Bbase);
    i32x8 b1 = *(const i32x8*)(Bbase + 2048);
    i32x8 b2 = *(const i32x8*)(Bbase + 4096);
    i32x8 b3 = *(const i32x8*)(Bbase + 6144);

    float partAcc[16] = {};

    #pragma unroll
    for (int nt = 0; nt < NT; ++nt) {
        f32x16 acc = {};

        #pragma unroll
        for (int k4 = 0; k4 < 4; ++k4) {
            const int s  = nt * 4 + k4;           // compile-time
            const int s4 = (s + 4 > NT * 4 - 1) ? (NT * 4 - 1) : (s + 4);

            __builtin_amdgcn_s_setprio(1);
            acc = __builtin_amdgcn_mfma_scale_f32_32x32x64_f8f6f4(
                (k4 == 0) ? a0 : (k4 == 1) ? a1 : (k4 == 2) ? a2 : a3,
                (s % 4 == 0) ? b0 : (s % 4 == 1) ? b1
                             : (s % 4 == 2) ? b2 : b3,
                acc,
                0, 0,                 // cbsz=fp8(A), blgp=fp8(B)
                0, 0x00000080,        // scale A = 2.0 (1/T)
                0, 0x0000007F);       // scale B = 1.0
            __builtin_amdgcn_s_setprio(0);

            // refill this slot for step s+4 (distance 4)
            if (s % 4 == 0)      { b0 = *(const i32x8*)(Bbase + (size_t)s4 * 2048); }
            else if (s % 4 == 1) { b1 = *(const i32x8*)(Bbase + (size_t)s4 * 2048); }
            else if (s % 4 == 2) { b2 = *(const i32x8*)(Bbase + (size_t)s4 * 2048); }
            else                 { b3 = *(const i32x8*)(Bbase + (size_t)s4 * 2048); }
        }

        // per-tile epilogue: bare exp2 + in-lane partial sums
        #pragma unroll
        for (int r = 0; r < 16; ++r)
            partAcc[r] += exp2f(acc[r]);
    }

    // wave epilogue: reduce across the 32 column-lanes (xor<32 stays in half)
    #pragma unroll
    for (int off = 1; off <= 16; off <<= 1)
        #pragma unroll
        for (int r = 0; r < 16; ++r)
            partAcc[r] += __shfl_xor(partAcc[r], off);

    if ((l & 31) == 0) {
        const int hi = l >> 5;           // C/D: row = (r&3) + 8*(r>>2) + 4*hi
        #pragma unroll
        for (int r = 0; r < 16; ++r) {
            const int rr = (r & 3) + 8 * (r >> 2) + 4 * hi;
            atomicAdd(&rowsum[rowBase + w * 32 + rr], partAcc[r]);
        }
    }
}

// ---------------------------------------------------------------------------
// Kernel 3: loss = mean_b [ log(exp(pos_b) + rowsum_b) - pos_b ]
// ---------------------------------------------------------------------------
__global__ __launch_bounds__(1024) void finalize_kernel(
    const float* __restrict__ pos_logit, const float* __restrict__ rowsum,
    float* __restrict__ out, int B)
{
    __shared__ float red[1024];
    float acc = 0.f;
    for (int b = (int)threadIdx.x; b < B; b += 1024) {
        const float pl = pos_logit[b];
        acc += logf(expf(pl) + rowsum[b]) - pl;
    }
    red[threadIdx.x] = acc;
    __syncthreads();
    #pragma unroll
    for (int s = 512; s; s >>= 1) {
        if ((int)threadIdx.x < s) red[threadIdx.x] += red[threadIdx.x + s];
        __syncthreads();
    }
    if (threadIdx.x == 0) out[0] = red[0] / (float)B;
}

// ---------------------------------------------------------------------------
extern "C" void kernel_launch(void* const* d_in, const int* in_sizes, int n_in,
                              void* d_out, int out_size, void* d_ws, size_t ws_size,
                              hipStream_t stream)
{
    const float* ei = (const float*)d_in[0];
    const float* ej = (const float*)d_in[1];
    const float* ek = (const float*)d_in[2];
    const int B = in_sizes[0] / D_DIM;   // 8192

    unsigned char* zip = (unsigned char*)d_ws;              // 2 MB packed fp8
    unsigned char* zkp = zip + (size_t)B * D_DIM;           // 2 MB packed fp8
    float* rowsum      = (float*)(zkp + (size_t)B * D_DIM);
    float* pos_logit   = rowsum + B;

    prep_kernel<<<dim3(B / 16), dim3(256), 0, stream>>>(
        ei, ej, ek, zip, zkp, pos_logit, rowsum);

    // grid: x = ROW blocks (fast -> each XCD L2 holds one B panel at a time),
    //       y = COL blocks
    dim3 grid(B / BM, B / (NT * 32));    // (64, 16) = 1024 blocks
    sim_mfma_kernel<<<grid, dim3(256), 0, stream>>>(zip, zkp, rowsum);

    finalize_kernel<<<dim3(1), dim3(1024), 0, stream>>>(
        pos_logit, rowsum, (float*)d_out, B);
}